// Round 1
// baseline (888.222 us; speedup 1.0000x reference)
//
#include <hip/hip_runtime.h>
#include <math.h>

// Problem constants (fixed by setup_inputs)
#define B_    8
#define T_    8192
#define LIN   1536
#define D_    768
#define H_    8
#define E_    96
#define TPB   16            // tokens per block in kernel 1
#define S_    20            // padded LDS stride (words) for transposed xn tile
#define NCH   256           // token chunks per batch in kernel 3
#define CHT   (T_ / NCH)    // 32 tokens per chunk

static __device__ __forceinline__ float resize_w(int j, int* i0, int* i1) {
    const float SCALE = (float)(1535.0 / 767.0);   // (L_IN-1)/(D-1), f32 like jnp
    float pos = (float)j * SCALE;
    int a = (int)floorf(pos);
    if (a > LIN - 1) a = LIN - 1;
    int b = a + 1 < LIN ? a + 1 : LIN - 1;
    *i0 = a; *i1 = b;
    return pos - (float)a;
}

// ---------------------------------------------------------------------------
// Kernel 1: per-token resize + LayerNorm + gated ABMIL head -> raw score s[b,t]
// One block = 16 tokens, 256 threads.
// ---------------------------------------------------------------------------
__global__ __launch_bounds__(256, 2)
void k1_score(const float* __restrict__ x,
              const float* __restrict__ gamma, const float* __restrict__ beta,
              const float* __restrict__ Wa, const float* __restrict__ ba,
              const float* __restrict__ Wb, const float* __restrict__ bb,
              const float* __restrict__ Wc, const float* __restrict__ bc,
              float* __restrict__ s_out)
{
    __shared__ float xnt[D_ * S_];   // transposed xn tile: [j=768][tok=16 pad 20]
    __shared__ float red[128];

    const int tid  = threadIdx.x;
    const int lane = tid & 63;
    const int wv   = tid >> 6;
    const int bt0  = blockIdx.x * TPB;

    // hoist LN params for this thread's 3 columns
    float gm[3], bt[3];
    int   idx0[3], idx1[3];
    float wlin[3];
    #pragma unroll
    for (int k = 0; k < 3; ++k) {
        int j = tid + k * 256;
        gm[k] = gamma[j];
        bt[k] = beta[j];
        wlin[k] = resize_w(j, &idx0[k], &idx1[k]);
    }

    // ---- Phase A: resize + LayerNorm, 16 tokens sequentially ----
    for (int tok = 0; tok < TPB; ++tok) {
        const float* xrow = x + (size_t)(bt0 + tok) * LIN;
        float xr[3];
        float sum = 0.0f, ssq = 0.0f;
        #pragma unroll
        for (int k = 0; k < 3; ++k) {
            float v = xrow[idx0[k]] * (1.0f - wlin[k]) + xrow[idx1[k]] * wlin[k];
            xr[k] = v; sum += v; ssq += v * v;
        }
        #pragma unroll
        for (int o = 32; o > 0; o >>= 1) {
            sum += __shfl_down(sum, o, 64);
            ssq += __shfl_down(ssq, o, 64);
        }
        if (lane == 0) { red[wv * 2] = sum; red[wv * 2 + 1] = ssq; }
        __syncthreads();
        float s0 = red[0] + red[2] + red[4] + red[6];
        float q0 = red[1] + red[3] + red[5] + red[7];
        float mu = s0 * (1.0f / D_);
        float var = q0 * (1.0f / D_) - mu * mu;
        float rs = 1.0f / sqrtf(var + 1e-5f);
        #pragma unroll
        for (int k = 0; k < 3; ++k) {
            int j = tid + k * 256;
            xnt[j * S_ + tok] = (xr[k] - mu) * rs * gm[k] + bt[k];
        }
        __syncthreads();
    }

    // ---- Phase B: gated ABMIL. Each thread owns 3 f's with one fixed h. ----
    const int h  = tid & 7;
    const int fb = tid >> 3;   // 0..31; f in {fb, fb+32, fb+64}
    const float* wA = Wa + h * (E_ * E_);
    const float* wB = Wb + h * (E_ * E_);

    float aacc[3][TPB], gacc[3][TPB];
    #pragma unroll
    for (int k = 0; k < 3; ++k)
        #pragma unroll
        for (int t = 0; t < TPB; ++t) { aacc[k][t] = 0.0f; gacc[k][t] = 0.0f; }

    #pragma unroll 2
    for (int e = 0; e < E_; ++e) {
        const float4* xp = (const float4*)&xnt[(e * 8 + h) * S_];
        float4 a0 = xp[0], a1 = xp[1], a2 = xp[2], a3 = xp[3];
        float xv[16] = { a0.x, a0.y, a0.z, a0.w, a1.x, a1.y, a1.z, a1.w,
                         a2.x, a2.y, a2.z, a2.w, a3.x, a3.y, a3.z, a3.w };
        #pragma unroll
        for (int k = 0; k < 3; ++k) {
            float wa = wA[e * E_ + fb + k * 32];
            float wb = wB[e * E_ + fb + k * 32];
            #pragma unroll
            for (int t = 0; t < TPB; ++t) {
                aacc[k][t] = fmaf(xv[t], wa, aacc[k][t]);
                gacc[k][t] = fmaf(xv[t], wb, gacc[k][t]);
            }
        }
    }

    float contrib[TPB];
    #pragma unroll
    for (int t = 0; t < TPB; ++t) contrib[t] = 0.0f;
    #pragma unroll
    for (int k = 0; k < 3; ++k) {
        int f = fb + k * 32;
        float bav = ba[h * E_ + f];
        float bbv = bb[h * E_ + f];
        float wcv = Wc[h * E_ + f];
        #pragma unroll
        for (int t = 0; t < TPB; ++t) {
            float av = tanhf(aacc[k][t] + bav);
            float gv = 1.0f / (1.0f + expf(-(gacc[k][t] + bbv)));
            contrib[t] = fmaf(av * gv, wcv, contrib[t]);
        }
    }

    #pragma unroll
    for (int t = 0; t < TPB; ++t) {
        float v = contrib[t];
        #pragma unroll
        for (int o = 32; o > 0; o >>= 1) v += __shfl_down(v, o, 64);
        if (lane == 0) red[wv * TPB + t] = v;
    }
    __syncthreads();
    if (tid < TPB) {
        float v = red[tid] + red[TPB + tid] + red[2 * TPB + tid] + red[3 * TPB + tid];
        float bcsum = 0.0f;
        #pragma unroll
        for (int hh = 0; hh < H_; ++hh) bcsum += bc[hh];
        s_out[bt0 + tid] = (v + bcsum) * (1.0f / H_);
    }
}

// ---------------------------------------------------------------------------
// Kernel 2: softmax over T per batch; overwrite s with normalized weights.
// ---------------------------------------------------------------------------
__global__ __launch_bounds__(256)
void k2_softmax(float* __restrict__ s)
{
    __shared__ float red[8];
    const int b = blockIdx.x, tid = threadIdx.x, lane = tid & 63, wv = tid >> 6;
    float* sb = s + (size_t)b * T_;

    float m = -INFINITY;
    for (int t = tid; t < T_; t += 256) m = fmaxf(m, sb[t]);
    #pragma unroll
    for (int o = 32; o > 0; o >>= 1) m = fmaxf(m, __shfl_down(m, o, 64));
    if (lane == 0) red[wv] = m;
    __syncthreads();
    m = fmaxf(fmaxf(red[0], red[1]), fmaxf(red[2], red[3]));
    __syncthreads();

    float z = 0.0f;
    for (int t = tid; t < T_; t += 256) z += expf(sb[t] - m);
    #pragma unroll
    for (int o = 32; o > 0; o >>= 1) z += __shfl_down(z, o, 64);
    if (lane == 0) red[wv] = z;
    __syncthreads();
    z = red[0] + red[1] + red[2] + red[3];
    float inv = 1.0f / z;
    for (int t = tid; t < T_; t += 256) sb[t] = expf(sb[t] - m) * inv;
}

// ---------------------------------------------------------------------------
// Kernel 3: recompute xn per token, accumulate w_t * xn into per-chunk partials.
// grid = B*NCH blocks; block handles 32 tokens of one batch.
// ---------------------------------------------------------------------------
__global__ __launch_bounds__(256)
void k3_pool(const float* __restrict__ x,
             const float* __restrict__ gamma, const float* __restrict__ beta,
             const float* __restrict__ w,
             float* __restrict__ partial)
{
    __shared__ float red[8];
    const int tid = threadIdx.x, lane = tid & 63, wv = tid >> 6;
    const int b = blockIdx.x / NCH, ch = blockIdx.x % NCH;
    const int t0 = ch * CHT;

    float gm[3], btv[3], wlin[3];
    int idx0[3], idx1[3];
    #pragma unroll
    for (int k = 0; k < 3; ++k) {
        int j = tid + k * 256;
        gm[k] = gamma[j];
        btv[k] = beta[j];
        wlin[k] = resize_w(j, &idx0[k], &idx1[k]);
    }

    float acc[3] = {0.0f, 0.0f, 0.0f};
    for (int tt = 0; tt < CHT; ++tt) {
        int t = t0 + tt;
        const float* xrow = x + ((size_t)b * T_ + t) * LIN;
        float xr[3];
        float sum = 0.0f, ssq = 0.0f;
        #pragma unroll
        for (int k = 0; k < 3; ++k) {
            float v = xrow[idx0[k]] * (1.0f - wlin[k]) + xrow[idx1[k]] * wlin[k];
            xr[k] = v; sum += v; ssq += v * v;
        }
        #pragma unroll
        for (int o = 32; o > 0; o >>= 1) {
            sum += __shfl_down(sum, o, 64);
            ssq += __shfl_down(ssq, o, 64);
        }
        if (lane == 0) { red[wv * 2] = sum; red[wv * 2 + 1] = ssq; }
        __syncthreads();
        float s0 = red[0] + red[2] + red[4] + red[6];
        float q0 = red[1] + red[3] + red[5] + red[7];
        float mu = s0 * (1.0f / D_);
        float rs = 1.0f / sqrtf(q0 * (1.0f / D_) - mu * mu + 1e-5f);
        float wt = w[(size_t)b * T_ + t];
        #pragma unroll
        for (int k = 0; k < 3; ++k)
            acc[k] = fmaf(wt, (xr[k] - mu) * rs * gm[k] + btv[k], acc[k]);
        __syncthreads();
    }

    float* p = partial + (size_t)blockIdx.x * D_;
    #pragma unroll
    for (int k = 0; k < 3; ++k) p[tid + k * 256] = acc[k];
}

// ---------------------------------------------------------------------------
// Kernel 4: reduce NCH partials per batch -> out[b, 768]
// ---------------------------------------------------------------------------
__global__ __launch_bounds__(256)
void k4_reduce(const float* __restrict__ partial, float* __restrict__ out)
{
    const int b = blockIdx.x, tid = threadIdx.x;
    #pragma unroll
    for (int k = 0; k < 3; ++k) {
        int j = tid + k * 256;
        const float* p = partial + (size_t)b * NCH * D_ + j;
        float s = 0.0f;
        for (int c = 0; c < NCH; ++c) s += p[(size_t)c * D_];
        out[b * D_ + j] = s;
    }
}

// ---------------------------------------------------------------------------
extern "C" void kernel_launch(void* const* d_in, const int* in_sizes, int n_in,
                              void* d_out, int out_size, void* d_ws, size_t ws_size,
                              hipStream_t stream)
{
    const float* x     = (const float*)d_in[0];
    // d_in[1] = lens (unused: uniform == L_IN, reference ignores it)
    const float* gamma = (const float*)d_in[2];
    const float* beta  = (const float*)d_in[3];
    const float* Wa    = (const float*)d_in[4];
    const float* ba    = (const float*)d_in[5];
    const float* Wb    = (const float*)d_in[6];
    const float* bb    = (const float*)d_in[7];
    const float* Wc    = (const float*)d_in[8];
    const float* bc    = (const float*)d_in[9];
    float* out = (float*)d_out;

    float* ws      = (float*)d_ws;
    float* s       = ws;               // B*T raw scores -> softmax weights
    float* partial = ws + B_ * T_;     // B*NCH*D partial pooled features

    hipLaunchKernelGGL(k1_score, dim3(B_ * T_ / TPB), dim3(256), 0, stream,
                       x, gamma, beta, Wa, ba, Wb, bb, Wc, bc, s);
    hipLaunchKernelGGL(k2_softmax, dim3(B_), dim3(256), 0, stream, s);
    hipLaunchKernelGGL(k3_pool, dim3(B_ * NCH), dim3(256), 0, stream,
                       x, gamma, beta, s, partial);
    hipLaunchKernelGGL(k4_reduce, dim3(B_), dim3(256), 0, stream, partial, out);
}

// Round 2
// 744.185 us; speedup vs baseline: 1.1935x; 1.1935x over previous
//
#include <hip/hip_runtime.h>
#include <math.h>

// Problem constants (fixed by setup_inputs)
#define B_    8
#define T_    8192
#define LIN   1536
#define D_    768
#define H_    8
#define E_    96
#define TPB   16            // tokens per block in kernel 1
#define S_    20            // padded LDS stride (words); 80B rows keep b128 alignment
#define NCH   64            // token chunks per batch in kernel 3
#define CHT   (T_ / NCH)    // 128 tokens per chunk
#define TPW3  (CHT / 4)     // 32 tokens per wave in kernel 3

static __device__ __forceinline__ float resize_w(int j, int* i0, int* i1) {
    const float SCALE = (float)(1535.0 / 767.0);   // (L_IN-1)/(D-1), f32 like jnp
    float pos = (float)j * SCALE;
    int a = (int)floorf(pos);
    if (a > LIN - 1) a = LIN - 1;
    int b = a + 1 < LIN ? a + 1 : LIN - 1;
    *i0 = a; *i1 = b;
    return pos - (float)a;
}

static __device__ __forceinline__ float fast_sigmoid(float v) {
    return 1.0f / (1.0f + __expf(-v));
}
static __device__ __forceinline__ float fast_tanh(float v) {
    float t = __expf(-2.0f * v);
    return (1.0f - t) / (1.0f + t);
}

// ---------------------------------------------------------------------------
// Kernel 1: per-token resize + LayerNorm + gated ABMIL head -> raw score s[b,t]
// One block = 16 tokens, 256 threads = 4 waves.
// Phase A is wave-local (wave w owns tokens 4w..4w+3): shuffle-only LN
// reduction, no barriers. ONE __syncthreads before phase B.
// ---------------------------------------------------------------------------
__global__ __launch_bounds__(256, 2)
void k1_score(const float* __restrict__ x,
              const float* __restrict__ gamma, const float* __restrict__ beta,
              const float* __restrict__ Wa, const float* __restrict__ ba,
              const float* __restrict__ Wb, const float* __restrict__ bb,
              const float* __restrict__ Wc, const float* __restrict__ bc,
              float* __restrict__ s_out)
{
    __shared__ float xnt[D_ * S_];   // transposed xn tile: [j=768][tok=16 pad 20]
    __shared__ float red[64];

    const int tid  = threadIdx.x;
    const int lane = tid & 63;
    const int wv   = tid >> 6;
    const int bt0  = blockIdx.x * TPB;

    // ---- Phase A: resize + LayerNorm; each wave owns 4 tokens, 12 feats/lane.
    {
        float gm[12], bt[12], wl[12];
        int   i0[12], i1[12];
        #pragma unroll
        for (int k = 0; k < 12; ++k) {
            int j = lane + k * 64;
            gm[k] = gamma[j];
            bt[k] = beta[j];
            wl[k] = resize_w(j, &i0[k], &i1[k]);
        }

        #pragma unroll
        for (int tt = 0; tt < 4; ++tt) {
            const int tok = wv * 4 + tt;
            const float* xrow = x + (size_t)(bt0 + tok) * LIN;
            float xr[12];
            float sum = 0.0f, ssq = 0.0f;
            #pragma unroll
            for (int k = 0; k < 12; ++k) {
                float v = xrow[i0[k]] * (1.0f - wl[k]) + xrow[i1[k]] * wl[k];
                xr[k] = v; sum += v; ssq += v * v;
            }
            #pragma unroll
            for (int o = 1; o < 64; o <<= 1) {
                sum += __shfl_xor(sum, o, 64);
                ssq += __shfl_xor(ssq, o, 64);
            }
            float mu = sum * (1.0f / D_);
            float var = ssq * (1.0f / D_) - mu * mu;
            float rs = 1.0f / sqrtf(var + 1e-5f);
            #pragma unroll
            for (int k = 0; k < 12; ++k) {
                int j = lane + k * 64;
                xnt[j * S_ + tok] = (xr[k] - mu) * rs * gm[k] + bt[k];
            }
        }
    }
    __syncthreads();

    // ---- Phase B: gated ABMIL. Each thread owns 3 f's with one fixed h. ----
    const int h  = tid & 7;
    const int fb = tid >> 3;   // 0..31; f in {fb, fb+32, fb+64}
    const float* wA = Wa + h * (E_ * E_);
    const float* wB = Wb + h * (E_ * E_);

    float aacc[3][TPB], gacc[3][TPB];
    #pragma unroll
    for (int k = 0; k < 3; ++k)
        #pragma unroll
        for (int t = 0; t < TPB; ++t) { aacc[k][t] = 0.0f; gacc[k][t] = 0.0f; }

    #pragma unroll 2
    for (int e = 0; e < E_; ++e) {
        const float4* xp = (const float4*)&xnt[(e * 8 + h) * S_];
        float4 a0 = xp[0], a1 = xp[1], a2 = xp[2], a3 = xp[3];
        float xv[16] = { a0.x, a0.y, a0.z, a0.w, a1.x, a1.y, a1.z, a1.w,
                         a2.x, a2.y, a2.z, a2.w, a3.x, a3.y, a3.z, a3.w };
        #pragma unroll
        for (int k = 0; k < 3; ++k) {
            float wa = wA[e * E_ + fb + k * 32];
            float wb = wB[e * E_ + fb + k * 32];
            #pragma unroll
            for (int t = 0; t < TPB; ++t) {
                aacc[k][t] = fmaf(xv[t], wa, aacc[k][t]);
                gacc[k][t] = fmaf(xv[t], wb, gacc[k][t]);
            }
        }
    }

    float contrib[TPB];
    #pragma unroll
    for (int t = 0; t < TPB; ++t) contrib[t] = 0.0f;
    #pragma unroll
    for (int k = 0; k < 3; ++k) {
        int f = fb + k * 32;
        float bav = ba[h * E_ + f];
        float bbv = bb[h * E_ + f];
        float wcv = Wc[h * E_ + f];
        #pragma unroll
        for (int t = 0; t < TPB; ++t) {
            float av = fast_tanh(aacc[k][t] + bav);
            float gv = fast_sigmoid(gacc[k][t] + bbv);
            contrib[t] = fmaf(av * gv, wcv, contrib[t]);
        }
    }

    #pragma unroll
    for (int t = 0; t < TPB; ++t) {
        float v = contrib[t];
        #pragma unroll
        for (int o = 32; o > 0; o >>= 1) v += __shfl_down(v, o, 64);
        if (lane == 0) red[wv * TPB + t] = v;
    }
    __syncthreads();
    if (tid < TPB) {
        float v = red[tid] + red[TPB + tid] + red[2 * TPB + tid] + red[3 * TPB + tid];
        float bcsum = 0.0f;
        #pragma unroll
        for (int hh = 0; hh < H_; ++hh) bcsum += bc[hh];
        s_out[bt0 + tid] = (v + bcsum) * (1.0f / H_);
    }
}

// ---------------------------------------------------------------------------
// Kernel 2: softmax over T per batch; overwrite s with normalized weights.
// ---------------------------------------------------------------------------
__global__ __launch_bounds__(256)
void k2_softmax(float* __restrict__ s)
{
    __shared__ float red[8];
    const int b = blockIdx.x, tid = threadIdx.x, lane = tid & 63, wv = tid >> 6;
    float* sb = s + (size_t)b * T_;

    float m = -INFINITY;
    for (int t = tid; t < T_; t += 256) m = fmaxf(m, sb[t]);
    #pragma unroll
    for (int o = 32; o > 0; o >>= 1) m = fmaxf(m, __shfl_down(m, o, 64));
    if (lane == 0) red[wv] = m;
    __syncthreads();
    m = fmaxf(fmaxf(red[0], red[1]), fmaxf(red[2], red[3]));
    __syncthreads();

    float z = 0.0f;
    for (int t = tid; t < T_; t += 256) z += __expf(sb[t] - m);
    #pragma unroll
    for (int o = 32; o > 0; o >>= 1) z += __shfl_down(z, o, 64);
    if (lane == 0) red[wv] = z;
    __syncthreads();
    z = red[0] + red[1] + red[2] + red[3];
    float inv = 1.0f / z;
    for (int t = tid; t < T_; t += 256) sb[t] = __expf(sb[t] - m) * inv;
}

// ---------------------------------------------------------------------------
// Kernel 3: recompute xn per token, accumulate w_t * xn, wave-private, zero
// barriers. grid = B*NCH blocks; each wave handles 32 tokens of one chunk.
// ---------------------------------------------------------------------------
__global__ __launch_bounds__(256)
void k3_pool(const float* __restrict__ x,
             const float* __restrict__ gamma, const float* __restrict__ beta,
             const float* __restrict__ w,
             float* __restrict__ partial)
{
    const int tid = threadIdx.x, lane = tid & 63, wv = tid >> 6;
    const int b = blockIdx.x / NCH, ch = blockIdx.x % NCH;
    const int t0 = ch * CHT + wv * TPW3;

    float gm[12], btv[12], wl[12];
    int i0[12], i1[12];
    #pragma unroll
    for (int k = 0; k < 12; ++k) {
        int j = lane + k * 64;
        gm[k] = gamma[j];
        btv[k] = beta[j];
        wl[k] = resize_w(j, &i0[k], &i1[k]);
    }

    float acc[12];
    #pragma unroll
    for (int k = 0; k < 12; ++k) acc[k] = 0.0f;

    for (int tt = 0; tt < TPW3; ++tt) {
        int t = t0 + tt;
        const float* xrow = x + ((size_t)b * T_ + t) * LIN;
        float xr[12];
        float sum = 0.0f, ssq = 0.0f;
        #pragma unroll
        for (int k = 0; k < 12; ++k) {
            float v = xrow[i0[k]] * (1.0f - wl[k]) + xrow[i1[k]] * wl[k];
            xr[k] = v; sum += v; ssq += v * v;
        }
        #pragma unroll
        for (int o = 1; o < 64; o <<= 1) {
            sum += __shfl_xor(sum, o, 64);
            ssq += __shfl_xor(ssq, o, 64);
        }
        float mu = sum * (1.0f / D_);
        float rs = 1.0f / sqrtf(ssq * (1.0f / D_) - mu * mu + 1e-5f);
        float wt = w[(size_t)b * T_ + t];
        #pragma unroll
        for (int k = 0; k < 12; ++k)
            acc[k] = fmaf(wt, (xr[k] - mu) * rs * gm[k] + btv[k], acc[k]);
    }

    float* p = partial + ((size_t)blockIdx.x * 4 + wv) * D_;
    #pragma unroll
    for (int k = 0; k < 12; ++k) p[lane + k * 64] = acc[k];
}

// ---------------------------------------------------------------------------
// Kernel 4: reduce NCH*4 wave-partials per batch -> out[b, 768]
// ---------------------------------------------------------------------------
__global__ __launch_bounds__(256)
void k4_reduce(const float* __restrict__ partial, float* __restrict__ out)
{
    const int b = blockIdx.x, tid = threadIdx.x;
    const int NR = NCH * 4;
    #pragma unroll
    for (int k = 0; k < 3; ++k) {
        int j = tid + k * 256;
        const float* p = partial + (size_t)b * NR * D_ + j;
        float s = 0.0f;
        for (int c = 0; c < NR; ++c) s += p[(size_t)c * D_];
        out[b * D_ + j] = s;
    }
}

// ---------------------------------------------------------------------------
extern "C" void kernel_launch(void* const* d_in, const int* in_sizes, int n_in,
                              void* d_out, int out_size, void* d_ws, size_t ws_size,
                              hipStream_t stream)
{
    const float* x     = (const float*)d_in[0];
    // d_in[1] = lens (unused: uniform == L_IN, reference ignores it)
    const float* gamma = (const float*)d_in[2];
    const float* beta  = (const float*)d_in[3];
    const float* Wa    = (const float*)d_in[4];
    const float* ba    = (const float*)d_in[5];
    const float* Wb    = (const float*)d_in[6];
    const float* bb    = (const float*)d_in[7];
    const float* Wc    = (const float*)d_in[8];
    const float* bc    = (const float*)d_in[9];
    float* out = (float*)d_out;

    float* ws      = (float*)d_ws;
    float* s       = ws;               // B*T raw scores -> softmax weights
    float* partial = ws + B_ * T_;     // B*NCH*4*D wave-partial pooled features

    hipLaunchKernelGGL(k1_score, dim3(B_ * T_ / TPB), dim3(256), 0, stream,
                       x, gamma, beta, Wa, ba, Wb, bb, Wc, bc, s);
    hipLaunchKernelGGL(k2_softmax, dim3(B_), dim3(256), 0, stream, s);
    hipLaunchKernelGGL(k3_pool, dim3(B_ * NCH), dim3(256), 0, stream,
                       x, gamma, beta, s, partial);
    hipLaunchKernelGGL(k4_reduce, dim3(B_), dim3(256), 0, stream, partial, out);
}